// Round 12
// baseline (218.012 us; speedup 1.0000x reference)
//
#include <hip/hip_runtime.h>
#include <hip/hip_bf16.h>

// Sizes (fixed by the reference)
#define BB 32
#define RR 6
#define SS 512
#define DD 256
#define HH 64
#define FF 256

typedef short  short8 __attribute__((ext_vector_type(8)));
typedef short  short4v __attribute__((ext_vector_type(4)));
typedef float  f32x4  __attribute__((ext_vector_type(4)));
typedef unsigned short ushort_t;
typedef unsigned int   uint_t;

__device__ __forceinline__ ushort_t f2bf(float f) {
    __hip_bfloat16 b = __float2bfloat16(f);
    return __builtin_bit_cast(ushort_t, b);
}
__device__ __forceinline__ float bf2f(ushort_t u) {
    return __bfloat162float(__builtin_bit_cast(__hip_bfloat16, u));
}

// ---------------- merged convert: x (vectorized) + all weights, one launch ----------------
__global__ __launch_bounds__(256) void convert_all_kernel(
        const float* __restrict__ x,
        const float* __restrict__ Wq, const float* __restrict__ Wk, const float* __restrict__ Wv,
        const float* __restrict__ Wfc, const float* __restrict__ W1, const float* __restrict__ W2,
        ushort_t* __restrict__ xb, ushort_t* __restrict__ wT, ushort_t* __restrict__ w1T,
        ushort_t* __restrict__ w2T, ushort_t* __restrict__ wfcT) {
    int bid = blockIdx.x;
    if (bid < 4096) {
        int gid = bid * 256 + threadIdx.x;
        float4 fv = ((const float4*)x)[gid];
        short4v o;
        o[0] = (short)f2bf(fv.x); o[1] = (short)f2bf(fv.y);
        o[2] = (short)f2bf(fv.z); o[3] = (short)f2bf(fv.w);
        *(short4v*)(xb + (size_t)gid * 4) = o;
        return;
    }
    int gid = (bid - 4096) * 256 + threadIdx.x;    // 524288 total
    if (gid < 294912) {
        int n = gid >> 8, d = gid & 255;
        int r = n / 192, rem = n % 192;
        int which = rem >> 6, h = rem & 63;
        const float* W = which == 0 ? Wq : which == 1 ? Wk : Wv;
        wT[gid] = f2bf(W[(size_t)r * DD * HH + (size_t)d * HH + h]);
    } else if (gid < 360448) {
        int gg = gid - 294912;
        int f = gg >> 8, d = gg & 255;
        w1T[gg] = f2bf(W1[(size_t)d * FF + f]);
    } else if (gid < 425984) {
        int gg = gid - 360448;
        int d = gg >> 8, f = gg & 255;
        w2T[gg] = f2bf(W2[(size_t)f * DD + d]);
    } else {
        int gg = gid - 425984;
        int n = gg >> 6, h = gg & 63;              // n = r*256 + d
        int r = n >> 8, d = n & 255;
        wfcT[gg] = f2bf(Wfc[((size_t)r * HH + h) * DD + d]);
    }
}

// ---------------- Kernel A: QKV GEMM via MFMA, bf16 inputs, no LDS ----------------
__global__ __launch_bounds__(256) void qkv_mfma_kernel(
        const ushort_t* __restrict__ xb, const ushort_t* __restrict__ wT,
        ushort_t* __restrict__ q, ushort_t* __restrict__ k, ushort_t* __restrict__ v) {
    int bid = blockIdx.x;
    int id = (bid & 7) * 288 + (bid >> 3);         // XCD-contiguous
    int rt = id / 18, cw = id % 18;                // cw = r*3 + which
    int r = cw / 3, which = cw % 3;

    int tid = threadIdx.x;
    int wv = tid >> 6, l = tid & 63;
    int wr = wv >> 1, wc = wv & 1;
    int g = l >> 4, lc = l & 15;

    const ushort_t* Arow = xb + ((size_t)(rt * 128 + wr * 64 + lc)) * DD + g * 8;
    const ushort_t* Brow = wT + ((size_t)(cw * 64 + wc * 32 + lc)) * DD + g * 8;

    f32x4 acc[4][2] = {};
    #pragma unroll 4
    for (int ks = 0; ks < 8; ++ks) {
        short8 af[4], bf[2];
        #pragma unroll
        for (int m = 0; m < 4; ++m)
            af[m] = *(const short8*)(Arow + (size_t)m * 16 * DD + ks * 32);
        #pragma unroll
        for (int n = 0; n < 2; ++n)
            bf[n] = *(const short8*)(Brow + (size_t)n * 16 * DD + ks * 32);
        #pragma unroll
        for (int m = 0; m < 4; ++m)
            #pragma unroll
            for (int n = 0; n < 2; ++n)
                acc[m][n] = __builtin_amdgcn_mfma_f32_16x16x32_bf16(af[m], bf[n], acc[m][n], 0, 0, 0);
    }

    ushort_t* outb = which == 0 ? q : which == 1 ? k : v;
    #pragma unroll
    for (int m = 0; m < 4; ++m) {
        #pragma unroll
        for (int reg = 0; reg < 4; ++reg) {
            int grow = rt * 128 + wr * 64 + m * 16 + g * 4 + reg;
            int orow = ((grow >> 9) * RR + r) * SS + (grow & (SS - 1));
            #pragma unroll
            for (int n = 0; n < 2; ++n)
                outb[(size_t)orow * HH + wc * 32 + n * 16 + lc] = f2bf(acc[m][n][reg]);
        }
    }
}

// ---------------- Kernel B: flash MFMA attention, skip-max softmax ----------------
__global__ __launch_bounds__(256) void attn_mfma_kernel(
        const ushort_t* __restrict__ q, const ushort_t* __restrict__ k,
        const ushort_t* __restrict__ v, const int* __restrict__ mask,
        ushort_t* __restrict__ ctx) {
    int wg = blockIdx.x;
    int id = (wg & 7) * 192 + (wg >> 3);
    int br = id >> 3, qt = id & 7;

    __shared__ ushort_t K_lds[64 * 72];
    __shared__ ushort_t VT_lds[64 * 66];   // stride 66: dword stride 33 (coprime 32) -> 2-way free
    __shared__ ushort_t P_lds[4][16 * 72];

    int tid = threadIdx.x;
    int wv = tid >> 6, l = tid & 63;
    int g = l >> 4, lc = l & 15;

    int q0 = qt * 64 + wv * 16;
    const size_t base_kv = (size_t)br * SS * HH;

    short8 qf[2];
    #pragma unroll
    for (int kk = 0; kk < 2; ++kk)
        qf[kk] = *(const short8*)(q + ((size_t)br * SS + q0 + lc) * HH + kk * 32 + g * 8);

    f32x4 O[4] = {{0,0,0,0},{0,0,0,0},{0,0,0,0},{0,0,0,0}};
    float lrun[4] = {0.f, 0.f, 0.f, 0.f};

    const int* mb = mask + ((size_t)br * SS + q0) * SS;

    for (int t0 = 0; t0 < SS; t0 += 64) {
        __syncthreads();
        for (int c = tid; c < 512; c += 256) {
            int t = c >> 3, c8 = (c & 7) * 8;
            *(short8*)&K_lds[t * 72 + c8] =
                *(const short8*)(k + base_kv + (size_t)(t0 + t) * HH + c8);
        }
        {
            int h = tid & 63, tseg = tid >> 6;
            #pragma unroll
            for (int jj = 0; jj < 8; ++jj) {
                int t = tseg * 16 + jj * 2;
                uint_t p0 = v[base_kv + (size_t)(t0 + t) * HH + h];
                uint_t p1 = v[base_kv + (size_t)(t0 + t + 1) * HH + h];
                *(uint_t*)&VT_lds[h * 66 + t] = p0 | (p1 << 16);
            }
        }
        __syncthreads();

        f32x4 S[4];
        #pragma unroll
        for (int tc = 0; tc < 4; ++tc) {
            f32x4 c = {0, 0, 0, 0};
            #pragma unroll
            for (int kk = 0; kk < 2; ++kk) {
                short8 bf = *(const short8*)&K_lds[(tc * 16 + lc) * 72 + kk * 32 + g * 8];
                c = __builtin_amdgcn_mfma_f32_16x16x32_bf16(qf[kk], bf, c, 0, 0, 0);
            }
            S[tc] = c;
        }

        float psum[4] = {0.f, 0.f, 0.f, 0.f};
        ushort_t* Pw = P_lds[wv];
        #pragma unroll
        for (int tc = 0; tc < 4; ++tc)
            #pragma unroll
            for (int reg = 0; reg < 4; ++reg) {
                int qrow = 4 * g + reg;
                int mv = mb[(size_t)qrow * SS + t0 + tc * 16 + lc];
                float p = mv ? 0.f : __expf(S[tc][reg] * 0.125f);
                psum[reg] += p;
                Pw[(4 * g + reg) * 72 + tc * 16 + lc] = f2bf(p);
            }
        #pragma unroll
        for (int reg = 0; reg < 4; ++reg) {
            float ps = psum[reg];
            ps += __shfl_xor(ps, 1, 64);
            ps += __shfl_xor(ps, 2, 64);
            ps += __shfl_xor(ps, 4, 64);
            ps += __shfl_xor(ps, 8, 64);
            lrun[reg] += ps;
        }
        asm volatile("s_waitcnt lgkmcnt(0)" ::: "memory");

        #pragma unroll
        for (int ts = 0; ts < 2; ++ts) {
            short8 pa = *(const short8*)&Pw[lc * 72 + ts * 32 + g * 8];
            #pragma unroll
            for (int hb = 0; hb < 4; ++hb) {
                short8 vbf = *(const short8*)&VT_lds[(hb * 16 + lc) * 66 + ts * 32 + g * 8];
                O[hb] = __builtin_amdgcn_mfma_f32_16x16x32_bf16(pa, vbf, O[hb], 0, 0, 0);
            }
        }
    }

    ushort_t* cb = ctx + ((size_t)br * SS + q0) * HH;
    #pragma unroll
    for (int reg = 0; reg < 4; ++reg) {
        float inv = lrun[reg] > 0.f ? 1.f / lrun[reg] : 0.f;
        #pragma unroll
        for (int hb = 0; hb < 4; ++hb)
            cb[(size_t)(4 * g + reg) * HH + hb * 16 + lc] = f2bf(O[hb][reg] * inv);
    }
}

// ---------------- Kernel C: fused tail (R7 geometry) + software-pipelined phase 1 ----------------
// grid 512 = 8 XCD * 64: block = 32 rows x 256 cols, 4 waves 2x2.
// __launch_bounds__(256,2): VGPR cap 256 (was 84) so the 16 B-fragment loads per
// branch can ALL stay in flight; branch r+1's loads are issued before branch r's
// stats/LN (double-buffered fragment registers, fully unrolled -> static indices).
__global__ __launch_bounds__(256, 2) void fused_tail_kernel(
        const ushort_t* __restrict__ ctx, const ushort_t* __restrict__ wfcT,
        const float* __restrict__ x, const ushort_t* __restrict__ w1T,
        const ushort_t* __restrict__ w2T, float* __restrict__ out) {
    int bid = blockIdx.x;
    int rt = (bid & 7) * 64 + (bid >> 3);          // XCD-contiguous row tiles
    int b = rt >> 4, s0 = (rt & 15) * 32;

    int tid = threadIdx.x;
    int wv = tid >> 6, l = tid & 63;
    int wr = wv >> 1, wc = wv & 1;
    int g = l >> 4, lc = l & 15;

    __shared__ ushort_t s_lds[32 * 264];
    __shared__ ushort_t h_lds[32 * 264];
    __shared__ float red_s[32][2];
    __shared__ float red_q[32][2];

    float xres[8][4];
    #pragma unroll
    for (int hb = 0; hb < 8; ++hb)
        #pragma unroll
        for (int reg = 0; reg < 4; ++reg)
            xres[hb][reg] = x[((size_t)b * SS + s0 + wr * 16 + g * 4 + reg) * DD
                              + wc * 128 + hb * 16 + lc];

    float acc_ln[8][4] = {};

    // fragment double buffers (named, static indices only)
    short8 afA[2], afB[2];
    short8 bfA[2][8], bfB[2][8];

    const ushort_t* Ab0 = ctx + (((size_t)b * RR + 0) * SS + s0 + wr * 16 + lc) * HH + g * 8;
    const ushort_t* Bb0 = wfcT + ((size_t)0 * 256 + wc * 128 + lc) * HH + g * 8;
    #pragma unroll
    for (int ks = 0; ks < 2; ++ks) {
        afA[ks] = *(const short8*)(Ab0 + ks * 32);
        #pragma unroll
        for (int hb = 0; hb < 8; ++hb)
            bfA[ks][hb] = *(const short8*)(Bb0 + (size_t)hb * 16 * HH + ks * 32);
    }

    #pragma unroll
    for (int r = 0; r < RR; ++r) {
        // ---- compute branch r from the A-buffer set (or B on odd r)
        f32x4 acc[8] = {};
        if ((r & 1) == 0) {
            #pragma unroll
            for (int ks = 0; ks < 2; ++ks)
                #pragma unroll
                for (int hb = 0; hb < 8; ++hb)
                    acc[hb] = __builtin_amdgcn_mfma_f32_16x16x32_bf16(afA[ks], bfA[ks][hb], acc[hb], 0, 0, 0);
        } else {
            #pragma unroll
            for (int ks = 0; ks < 2; ++ks)
                #pragma unroll
                for (int hb = 0; hb < 8; ++hb)
                    acc[hb] = __builtin_amdgcn_mfma_f32_16x16x32_bf16(afB[ks], bfB[ks][hb], acc[hb], 0, 0, 0);
        }

        // ---- issue branch r+1 loads into the OTHER buffer set (fly during stats)
        if (r < RR - 1) {
            const ushort_t* Abn = ctx + (((size_t)b * RR + (r + 1)) * SS + s0 + wr * 16 + lc) * HH + g * 8;
            const ushort_t* Bbn = wfcT + ((size_t)(r + 1) * 256 + wc * 128 + lc) * HH + g * 8;
            if ((r & 1) == 0) {
                #pragma unroll
                for (int ks = 0; ks < 2; ++ks) {
                    afB[ks] = *(const short8*)(Abn + ks * 32);
                    #pragma unroll
                    for (int hb = 0; hb < 8; ++hb)
                        bfB[ks][hb] = *(const short8*)(Bbn + (size_t)hb * 16 * HH + ks * 32);
                }
            } else {
                #pragma unroll
                for (int ks = 0; ks < 2; ++ks) {
                    afA[ks] = *(const short8*)(Abn + ks * 32);
                    #pragma unroll
                    for (int hb = 0; hb < 8; ++hb)
                        bfA[ks][hb] = *(const short8*)(Bbn + (size_t)hb * 16 * HH + ks * 32);
                }
            }
        }

        // ---- residual + stats + LN for branch r (loads for r+1 in flight)
        float vals[8][4];
        float psum[4] = {0, 0, 0, 0}, psq[4] = {0, 0, 0, 0};
        #pragma unroll
        for (int hb = 0; hb < 8; ++hb)
            #pragma unroll
            for (int reg = 0; reg < 4; ++reg) {
                float vv = acc[hb][reg] + xres[hb][reg];
                vals[hb][reg] = vv;
                psum[reg] += vv;
                psq[reg]  += vv * vv;
            }
        #pragma unroll
        for (int reg = 0; reg < 4; ++reg) {
            #pragma unroll
            for (int off = 1; off <= 8; off <<= 1) {
                psum[reg] += __shfl_xor(psum[reg], off, 64);
                psq[reg]  += __shfl_xor(psq[reg],  off, 64);
            }
        }
        if (lc == 0) {
            #pragma unroll
            for (int reg = 0; reg < 4; ++reg) {
                int row = wr * 16 + g * 4 + reg;
                red_s[row][wc] = psum[reg];
                red_q[row][wc] = psq[reg];
            }
        }
        __syncthreads();
        float mean_r[4], inv_r[4];
        #pragma unroll
        for (int reg = 0; reg < 4; ++reg) {
            int row = wr * 16 + g * 4 + reg;
            float sum = red_s[row][0] + red_s[row][1];
            float sq  = red_q[row][0] + red_q[row][1];
            float mean = sum * (1.f / 256.f);
            float var  = sq * (1.f / 256.f) - mean * mean;
            mean_r[reg] = mean;
            inv_r[reg]  = rsqrtf(var + 1e-5f);
        }
        #pragma unroll
        for (int hb = 0; hb < 8; ++hb)
            #pragma unroll
            for (int reg = 0; reg < 4; ++reg)
                acc_ln[hb][reg] += (vals[hb][reg] - mean_r[reg]) * inv_r[reg];
        __syncthreads();   // red reuse-safe
    }

    // s -> LDS (bf16, same rounding point as before)
    #pragma unroll
    for (int hb = 0; hb < 8; ++hb)
        #pragma unroll
        for (int reg = 0; reg < 4; ++reg) {
            int row = wr * 16 + g * 4 + reg;
            int col = wc * 128 + hb * 16 + lc;
            s_lds[row * 264 + col] = f2bf(acc_ln[hb][reg]);
        }

    // prefetch phase-2 ks=0 weight fragments across the barrier
    short8 b1f[8];
    #pragma unroll
    for (int hb = 0; hb < 8; ++hb)
        b1f[hb] = *(const short8*)(w1T + (size_t)(wc * 128 + hb * 16 + lc) * DD + g * 8);
    __syncthreads();

    // ---- phase 2: FFN GEMM1 (relu) ----
    f32x4 acc1[8] = {};
    {
        short8 af = *(const short8*)&s_lds[(wr * 16 + lc) * 264 + g * 8];
        #pragma unroll
        for (int hb = 0; hb < 8; ++hb)
            acc1[hb] = __builtin_amdgcn_mfma_f32_16x16x32_bf16(af, b1f[hb], acc1[hb], 0, 0, 0);
    }
    #pragma unroll
    for (int ks = 1; ks < 8; ++ks) {
        short8 af = *(const short8*)&s_lds[(wr * 16 + lc) * 264 + ks * 32 + g * 8];
        #pragma unroll
        for (int hb = 0; hb < 8; ++hb) {
            short8 bf = *(const short8*)(w1T + (size_t)(wc * 128 + hb * 16 + lc) * DD + ks * 32 + g * 8);
            acc1[hb] = __builtin_amdgcn_mfma_f32_16x16x32_bf16(af, bf, acc1[hb], 0, 0, 0);
        }
    }
    #pragma unroll
    for (int hb = 0; hb < 8; ++hb)
        #pragma unroll
        for (int reg = 0; reg < 4; ++reg) {
            int row = wr * 16 + g * 4 + reg;
            int col = wc * 128 + hb * 16 + lc;
            h_lds[row * 264 + col] = f2bf(fmaxf(acc1[hb][reg], 0.f));
        }

    // prefetch phase-3 ks=0 weight fragments across the barrier
    short8 b2f[8];
    #pragma unroll
    for (int hb = 0; hb < 8; ++hb)
        b2f[hb] = *(const short8*)(w2T + (size_t)(wc * 128 + hb * 16 + lc) * FF + g * 8);
    __syncthreads();

    // ---- phase 3: FFN GEMM2 + residual + LN ----
    f32x4 acc2[8] = {};
    {
        short8 af = *(const short8*)&h_lds[(wr * 16 + lc) * 264 + g * 8];
        #pragma unroll
        for (int hb = 0; hb < 8; ++hb)
            acc2[hb] = __builtin_amdgcn_mfma_f32_16x16x32_bf16(af, b2f[hb], acc2[hb], 0, 0, 0);
    }
    #pragma unroll
    for (int ks = 1; ks < 8; ++ks) {
        short8 af = *(const short8*)&h_lds[(wr * 16 + lc) * 264 + ks * 32 + g * 8];
        #pragma unroll
        for (int hb = 0; hb < 8; ++hb) {
            short8 bf = *(const short8*)(w2T + (size_t)(wc * 128 + hb * 16 + lc) * FF + ks * 32 + g * 8);
            acc2[hb] = __builtin_amdgcn_mfma_f32_16x16x32_bf16(af, bf, acc2[hb], 0, 0, 0);
        }
    }

    float vals[8][4];
    float psum[4] = {0, 0, 0, 0}, psq[4] = {0, 0, 0, 0};
    #pragma unroll
    for (int hb = 0; hb < 8; ++hb)
        #pragma unroll
        for (int reg = 0; reg < 4; ++reg) {
            int row = wr * 16 + g * 4 + reg;
            int col = wc * 128 + hb * 16 + lc;
            float vv = acc2[hb][reg] + bf2f(s_lds[row * 264 + col]);
            vals[hb][reg] = vv;
            psum[reg] += vv;
            psq[reg]  += vv * vv;
        }
    #pragma unroll
    for (int reg = 0; reg < 4; ++reg) {
        #pragma unroll
        for (int off = 1; off <= 8; off <<= 1) {
            psum[reg] += __shfl_xor(psum[reg], off, 64);
            psq[reg]  += __shfl_xor(psq[reg],  off, 64);
        }
    }
    if (lc == 0) {
        #pragma unroll
        for (int reg = 0; reg < 4; ++reg) {
            int row = wr * 16 + g * 4 + reg;
            red_s[row][wc] = psum[reg];
            red_q[row][wc] = psq[reg];
        }
    }
    __syncthreads();
    float mean_r[4], inv_r[4];
    #pragma unroll
    for (int reg = 0; reg < 4; ++reg) {
        int row = wr * 16 + g * 4 + reg;
        float sum = red_s[row][0] + red_s[row][1];
        float sq  = red_q[row][0] + red_q[row][1];
        float mean = sum * (1.f / 256.f);
        float var  = sq * (1.f / 256.f) - mean * mean;
        mean_r[reg] = mean;
        inv_r[reg]  = rsqrtf(var + 1e-5f);
    }
    #pragma unroll
    for (int hb = 0; hb < 8; ++hb)
        #pragma unroll
        for (int reg = 0; reg < 4; ++reg) {
            int row = wr * 16 + g * 4 + reg;
            int col = wc * 128 + hb * 16 + lc;
            out[((size_t)rt * 32 + row) * DD + col] = (vals[hb][reg] - mean_r[reg]) * inv_r[reg];
        }
}

// ---------------- launch ----------------
extern "C" void kernel_launch(void* const* d_in, const int* in_sizes, int n_in,
                              void* d_out, int out_size, void* d_ws, size_t ws_size,
                              hipStream_t stream) {
    const float* x    = (const float*)d_in[0];
    const int*   mask = (const int*)  d_in[1];
    const float* Wq   = (const float*)d_in[2];
    const float* Wk   = (const float*)d_in[3];
    const float* Wv   = (const float*)d_in[4];
    const float* Wfc  = (const float*)d_in[5];
    const float* W1   = (const float*)d_in[6];
    const float* W2   = (const float*)d_in[7];
    float* out = (float*)d_out;

    const size_t QKV = (size_t)BB * RR * SS * HH;   // 6,291,456 elements
    const size_t BSD = (size_t)BB * SS * DD;        // 4,194,304 elements
    ushort_t* qb  = (ushort_t*)d_ws;                // bf16
    ushort_t* kb  = qb + QKV;
    ushort_t* vb  = kb + QKV;
    ushort_t* ctx = vb + QKV;                       // bf16 [B,6,S,64]
    ushort_t* xb  = ctx + QKV;                      // bf16 [B*S,256]
    ushort_t* wT  = xb + BSD;                       // bf16 [1152,256]
    ushort_t* w1T = wT + (size_t)1152 * 256;        // bf16 [256,256]
    ushort_t* w2T = w1T + 65536;                    // bf16 [256,256]
    ushort_t* wfcT = w2T + 65536;                   // bf16 [6*256,64]

    convert_all_kernel<<<6144, 256, 0, stream>>>(x, Wq, Wk, Wv, Wfc, W1, W2,
                                                 xb, wT, w1T, w2T, wfcT);
    qkv_mfma_kernel  <<<2304, 256, 0, stream>>>(xb, wT, qb, kb, vb);
    attn_mfma_kernel <<<BB * RR * 8, 256, 0, stream>>>(qb, kb, vb, mask, ctx);
    fused_tail_kernel<<<512, 256, 0, stream>>>(ctx, wfcT, x, w1T, w2T, out);
}

// Round 13
// 192.530 us; speedup vs baseline: 1.1324x; 1.1324x over previous
//
#include <hip/hip_runtime.h>
#include <hip/hip_bf16.h>

// Sizes (fixed by the reference)
#define BB 32
#define RR 6
#define SS 512
#define DD 256
#define HH 64
#define FF 256

typedef short  short8 __attribute__((ext_vector_type(8)));
typedef short  short4v __attribute__((ext_vector_type(4)));
typedef float  f32x4  __attribute__((ext_vector_type(4)));
typedef unsigned short ushort_t;
typedef unsigned int   uint_t;

__device__ __forceinline__ ushort_t f2bf(float f) {
    __hip_bfloat16 b = __float2bfloat16(f);
    return __builtin_bit_cast(ushort_t, b);
}
__device__ __forceinline__ float bf2f(ushort_t u) {
    return __bfloat162float(__builtin_bit_cast(__hip_bfloat16, u));
}

// ---------------- merged convert: x (vectorized) + all weights, one launch ----------------
__global__ __launch_bounds__(256) void convert_all_kernel(
        const float* __restrict__ x,
        const float* __restrict__ Wq, const float* __restrict__ Wk, const float* __restrict__ Wv,
        const float* __restrict__ Wfc, const float* __restrict__ W1, const float* __restrict__ W2,
        ushort_t* __restrict__ xb, ushort_t* __restrict__ wT, ushort_t* __restrict__ w1T,
        ushort_t* __restrict__ w2T, ushort_t* __restrict__ wfcT) {
    int bid = blockIdx.x;
    if (bid < 4096) {
        int gid = bid * 256 + threadIdx.x;
        float4 fv = ((const float4*)x)[gid];
        short4v o;
        o[0] = (short)f2bf(fv.x); o[1] = (short)f2bf(fv.y);
        o[2] = (short)f2bf(fv.z); o[3] = (short)f2bf(fv.w);
        *(short4v*)(xb + (size_t)gid * 4) = o;
        return;
    }
    int gid = (bid - 4096) * 256 + threadIdx.x;    // 524288 total
    if (gid < 294912) {
        int n = gid >> 8, d = gid & 255;
        int r = n / 192, rem = n % 192;
        int which = rem >> 6, h = rem & 63;
        const float* W = which == 0 ? Wq : which == 1 ? Wk : Wv;
        wT[gid] = f2bf(W[(size_t)r * DD * HH + (size_t)d * HH + h]);
    } else if (gid < 360448) {
        int gg = gid - 294912;
        int f = gg >> 8, d = gg & 255;
        w1T[gg] = f2bf(W1[(size_t)d * FF + f]);
    } else if (gid < 425984) {
        int gg = gid - 360448;
        int d = gg >> 8, f = gg & 255;
        w2T[gg] = f2bf(W2[(size_t)f * DD + d]);
    } else {
        int gg = gid - 425984;
        int n = gg >> 6, h = gg & 63;              // n = r*256 + d
        int r = n >> 8, d = n & 255;
        wfcT[gg] = f2bf(Wfc[((size_t)r * HH + h) * DD + d]);
    }
}

// ---------------- Kernel A: QKV GEMM via MFMA, bf16 inputs, no LDS ----------------
__global__ __launch_bounds__(256) void qkv_mfma_kernel(
        const ushort_t* __restrict__ xb, const ushort_t* __restrict__ wT,
        ushort_t* __restrict__ q, ushort_t* __restrict__ k, ushort_t* __restrict__ v) {
    int bid = blockIdx.x;
    int id = (bid & 7) * 288 + (bid >> 3);         // XCD-contiguous
    int rt = id / 18, cw = id % 18;                // cw = r*3 + which
    int r = cw / 3, which = cw % 3;

    int tid = threadIdx.x;
    int wv = tid >> 6, l = tid & 63;
    int wr = wv >> 1, wc = wv & 1;
    int g = l >> 4, lc = l & 15;

    const ushort_t* Arow = xb + ((size_t)(rt * 128 + wr * 64 + lc)) * DD + g * 8;
    const ushort_t* Brow = wT + ((size_t)(cw * 64 + wc * 32 + lc)) * DD + g * 8;

    f32x4 acc[4][2] = {};
    #pragma unroll 4
    for (int ks = 0; ks < 8; ++ks) {
        short8 af[4], bf[2];
        #pragma unroll
        for (int m = 0; m < 4; ++m)
            af[m] = *(const short8*)(Arow + (size_t)m * 16 * DD + ks * 32);
        #pragma unroll
        for (int n = 0; n < 2; ++n)
            bf[n] = *(const short8*)(Brow + (size_t)n * 16 * DD + ks * 32);
        #pragma unroll
        for (int m = 0; m < 4; ++m)
            #pragma unroll
            for (int n = 0; n < 2; ++n)
                acc[m][n] = __builtin_amdgcn_mfma_f32_16x16x32_bf16(af[m], bf[n], acc[m][n], 0, 0, 0);
    }

    ushort_t* outb = which == 0 ? q : which == 1 ? k : v;
    #pragma unroll
    for (int m = 0; m < 4; ++m) {
        #pragma unroll
        for (int reg = 0; reg < 4; ++reg) {
            int grow = rt * 128 + wr * 64 + m * 16 + g * 4 + reg;
            int orow = ((grow >> 9) * RR + r) * SS + (grow & (SS - 1));
            #pragma unroll
            for (int n = 0; n < 2; ++n)
                outb[(size_t)orow * HH + wc * 32 + n * 16 + lc] = f2bf(acc[m][n][reg]);
        }
    }
}

// ---------------- Kernel B: flash MFMA attention, skip-max softmax ----------------
__global__ __launch_bounds__(256) void attn_mfma_kernel(
        const ushort_t* __restrict__ q, const ushort_t* __restrict__ k,
        const ushort_t* __restrict__ v, const int* __restrict__ mask,
        ushort_t* __restrict__ ctx) {
    int wg = blockIdx.x;
    int id = (wg & 7) * 192 + (wg >> 3);
    int br = id >> 3, qt = id & 7;

    __shared__ ushort_t K_lds[64 * 72];
    __shared__ ushort_t VT_lds[64 * 66];   // stride 66: dword stride 33 (coprime 32) -> 2-way free
    __shared__ ushort_t P_lds[4][16 * 72];

    int tid = threadIdx.x;
    int wv = tid >> 6, l = tid & 63;
    int g = l >> 4, lc = l & 15;

    int q0 = qt * 64 + wv * 16;
    const size_t base_kv = (size_t)br * SS * HH;

    short8 qf[2];
    #pragma unroll
    for (int kk = 0; kk < 2; ++kk)
        qf[kk] = *(const short8*)(q + ((size_t)br * SS + q0 + lc) * HH + kk * 32 + g * 8);

    f32x4 O[4] = {{0,0,0,0},{0,0,0,0},{0,0,0,0},{0,0,0,0}};
    float lrun[4] = {0.f, 0.f, 0.f, 0.f};

    const int* mb = mask + ((size_t)br * SS + q0) * SS;

    for (int t0 = 0; t0 < SS; t0 += 64) {
        __syncthreads();
        for (int c = tid; c < 512; c += 256) {
            int t = c >> 3, c8 = (c & 7) * 8;
            *(short8*)&K_lds[t * 72 + c8] =
                *(const short8*)(k + base_kv + (size_t)(t0 + t) * HH + c8);
        }
        {
            int h = tid & 63, tseg = tid >> 6;
            #pragma unroll
            for (int jj = 0; jj < 8; ++jj) {
                int t = tseg * 16 + jj * 2;
                uint_t p0 = v[base_kv + (size_t)(t0 + t) * HH + h];
                uint_t p1 = v[base_kv + (size_t)(t0 + t + 1) * HH + h];
                *(uint_t*)&VT_lds[h * 66 + t] = p0 | (p1 << 16);
            }
        }
        __syncthreads();

        f32x4 S[4];
        #pragma unroll
        for (int tc = 0; tc < 4; ++tc) {
            f32x4 c = {0, 0, 0, 0};
            #pragma unroll
            for (int kk = 0; kk < 2; ++kk) {
                short8 bf = *(const short8*)&K_lds[(tc * 16 + lc) * 72 + kk * 32 + g * 8];
                c = __builtin_amdgcn_mfma_f32_16x16x32_bf16(qf[kk], bf, c, 0, 0, 0);
            }
            S[tc] = c;
        }

        float psum[4] = {0.f, 0.f, 0.f, 0.f};
        ushort_t* Pw = P_lds[wv];
        #pragma unroll
        for (int tc = 0; tc < 4; ++tc)
            #pragma unroll
            for (int reg = 0; reg < 4; ++reg) {
                int qrow = 4 * g + reg;
                int mv = mb[(size_t)qrow * SS + t0 + tc * 16 + lc];
                float p = mv ? 0.f : __expf(S[tc][reg] * 0.125f);
                psum[reg] += p;
                Pw[(4 * g + reg) * 72 + tc * 16 + lc] = f2bf(p);
            }
        #pragma unroll
        for (int reg = 0; reg < 4; ++reg) {
            float ps = psum[reg];
            ps += __shfl_xor(ps, 1, 64);
            ps += __shfl_xor(ps, 2, 64);
            ps += __shfl_xor(ps, 4, 64);
            ps += __shfl_xor(ps, 8, 64);
            lrun[reg] += ps;
        }
        asm volatile("s_waitcnt lgkmcnt(0)" ::: "memory");

        #pragma unroll
        for (int ts = 0; ts < 2; ++ts) {
            short8 pa = *(const short8*)&Pw[lc * 72 + ts * 32 + g * 8];
            #pragma unroll
            for (int hb = 0; hb < 4; ++hb) {
                short8 vbf = *(const short8*)&VT_lds[(hb * 16 + lc) * 66 + ts * 32 + g * 8];
                O[hb] = __builtin_amdgcn_mfma_f32_16x16x32_bf16(pa, vbf, O[hb], 0, 0, 0);
            }
        }
    }

    ushort_t* cb = ctx + ((size_t)br * SS + q0) * HH;
    #pragma unroll
    for (int reg = 0; reg < 4; ++reg) {
        float inv = lrun[reg] > 0.f ? 1.f / lrun[reg] : 0.f;
        #pragma unroll
        for (int hb = 0; hb < 4; ++hb)
            cb[(size_t)(4 * g + reg) * HH + hb * 16 + lc] = f2bf(O[hb][reg] * inv);
    }
}

// ---------------- Kernel C: fused tail (R11 base) — ONE barrier per branch ----------------
// grid 512 = 8 XCD * 64: block = 32 rows x 256 cols, 4 waves 2x2.
// red buffers are per-branch slices: branch r stashes into red_*[r], ONE barrier
// publishes it, and the WAR hazard on slice r+1 is protected by barrier r+1.
// Phase-1 barrier count 12 -> 6 (block total 15 -> 9). No register prefetch across
// barriers (defeated by the vmcnt(0) drain __syncthreads implies on CDNA4).
__global__ __launch_bounds__(256) void fused_tail_kernel(
        const ushort_t* __restrict__ ctx, const ushort_t* __restrict__ wfcT,
        const float* __restrict__ x, const ushort_t* __restrict__ w1T,
        const ushort_t* __restrict__ w2T, float* __restrict__ out) {
    int bid = blockIdx.x;
    int rt = (bid & 7) * 64 + (bid >> 3);          // XCD-contiguous row tiles
    int b = rt >> 4, s0 = (rt & 15) * 32;

    int tid = threadIdx.x;
    int wv = tid >> 6, l = tid & 63;
    int wr = wv >> 1, wc = wv & 1;
    int g = l >> 4, lc = l & 15;

    __shared__ ushort_t s_lds[32 * 264];
    __shared__ ushort_t h_lds[32 * 264];
    __shared__ float red_s[RR][32][2];
    __shared__ float red_q[RR][32][2];

    float xres[8][4];
    #pragma unroll
    for (int hb = 0; hb < 8; ++hb)
        #pragma unroll
        for (int reg = 0; reg < 4; ++reg)
            xres[hb][reg] = x[((size_t)b * SS + s0 + wr * 16 + g * 4 + reg) * DD
                              + wc * 128 + hb * 16 + lc];

    float acc_ln[8][4] = {};

    for (int r = 0; r < RR; ++r) {
        const ushort_t* Abase = ctx + (((size_t)b * RR + r) * SS + s0 + wr * 16 + lc) * HH + g * 8;
        const ushort_t* Bbase = wfcT + ((size_t)r * 256 + wc * 128 + lc) * HH + g * 8;
        f32x4 acc[8] = {};
        #pragma unroll
        for (int ks = 0; ks < 2; ++ks) {
            short8 af = *(const short8*)(Abase + ks * 32);
            #pragma unroll
            for (int hb = 0; hb < 8; ++hb) {
                short8 bf = *(const short8*)(Bbase + (size_t)hb * 16 * HH + ks * 32);
                acc[hb] = __builtin_amdgcn_mfma_f32_16x16x32_bf16(af, bf, acc[hb], 0, 0, 0);
            }
        }

        float vals[8][4];
        float psum[4] = {0, 0, 0, 0}, psq[4] = {0, 0, 0, 0};
        #pragma unroll
        for (int hb = 0; hb < 8; ++hb)
            #pragma unroll
            for (int reg = 0; reg < 4; ++reg) {
                float vv = acc[hb][reg] + xres[hb][reg];
                vals[hb][reg] = vv;
                psum[reg] += vv;
                psq[reg]  += vv * vv;
            }
        #pragma unroll
        for (int reg = 0; reg < 4; ++reg) {
            #pragma unroll
            for (int off = 1; off <= 8; off <<= 1) {
                psum[reg] += __shfl_xor(psum[reg], off, 64);
                psq[reg]  += __shfl_xor(psq[reg],  off, 64);
            }
        }
        if (lc == 0) {
            #pragma unroll
            for (int reg = 0; reg < 4; ++reg) {
                int row = wr * 16 + g * 4 + reg;
                red_s[r][row][wc] = psum[reg];
                red_q[r][row][wc] = psq[reg];
            }
        }
        __syncthreads();                           // the ONE barrier for branch r
        #pragma unroll
        for (int reg = 0; reg < 4; ++reg) {
            int row = wr * 16 + g * 4 + reg;
            float sum = red_s[r][row][0] + red_s[r][row][1];
            float sq  = red_q[r][row][0] + red_q[r][row][1];
            float mean = sum * (1.f / 256.f);
            float var  = sq * (1.f / 256.f) - mean * mean;
            float inv  = rsqrtf(var + 1e-5f);
            #pragma unroll
            for (int hb = 0; hb < 8; ++hb)
                acc_ln[hb][reg] += (vals[hb][reg] - mean) * inv;
        }
    }

    // s -> LDS (bf16, same rounding point as before)
    #pragma unroll
    for (int hb = 0; hb < 8; ++hb)
        #pragma unroll
        for (int reg = 0; reg < 4; ++reg) {
            int row = wr * 16 + g * 4 + reg;
            int col = wc * 128 + hb * 16 + lc;
            s_lds[row * 264 + col] = f2bf(acc_ln[hb][reg]);
        }
    __syncthreads();

    // ---- phase 2: FFN GEMM1 (relu) ----
    f32x4 acc1[8] = {};
    #pragma unroll
    for (int ks = 0; ks < 8; ++ks) {
        short8 af = *(const short8*)&s_lds[(wr * 16 + lc) * 264 + ks * 32 + g * 8];
        #pragma unroll
        for (int hb = 0; hb < 8; ++hb) {
            short8 bf = *(const short8*)(w1T + (size_t)(wc * 128 + hb * 16 + lc) * DD + ks * 32 + g * 8);
            acc1[hb] = __builtin_amdgcn_mfma_f32_16x16x32_bf16(af, bf, acc1[hb], 0, 0, 0);
        }
    }
    #pragma unroll
    for (int hb = 0; hb < 8; ++hb)
        #pragma unroll
        for (int reg = 0; reg < 4; ++reg) {
            int row = wr * 16 + g * 4 + reg;
            int col = wc * 128 + hb * 16 + lc;
            h_lds[row * 264 + col] = f2bf(fmaxf(acc1[hb][reg], 0.f));
        }
    __syncthreads();

    // ---- phase 3: FFN GEMM2 + residual + LN ----
    f32x4 acc2[8] = {};
    #pragma unroll
    for (int ks = 0; ks < 8; ++ks) {
        short8 af = *(const short8*)&h_lds[(wr * 16 + lc) * 264 + ks * 32 + g * 8];
        #pragma unroll
        for (int hb = 0; hb < 8; ++hb) {
            short8 bf = *(const short8*)(w2T + (size_t)(wc * 128 + hb * 16 + lc) * FF + ks * 32 + g * 8);
            acc2[hb] = __builtin_amdgcn_mfma_f32_16x16x32_bf16(af, bf, acc2[hb], 0, 0, 0);
        }
    }

    float vals[8][4];
    float psum[4] = {0, 0, 0, 0}, psq[4] = {0, 0, 0, 0};
    #pragma unroll
    for (int hb = 0; hb < 8; ++hb)
        #pragma unroll
        for (int reg = 0; reg < 4; ++reg) {
            int row = wr * 16 + g * 4 + reg;
            int col = wc * 128 + hb * 16 + lc;
            float vv = acc2[hb][reg] + bf2f(s_lds[row * 264 + col]);
            vals[hb][reg] = vv;
            psum[reg] += vv;
            psq[reg]  += vv * vv;
        }
    #pragma unroll
    for (int reg = 0; reg < 4; ++reg) {
        #pragma unroll
        for (int off = 1; off <= 8; off <<= 1) {
            psum[reg] += __shfl_xor(psum[reg], off, 64);
            psq[reg]  += __shfl_xor(psq[reg],  off, 64);
        }
    }
    if (lc == 0) {
        #pragma unroll
        for (int reg = 0; reg < 4; ++reg) {
            int row = wr * 16 + g * 4 + reg;
            red_s[0][row][wc] = psum[reg];
            red_q[0][row][wc] = psq[reg];
        }
    }
    __syncthreads();
    #pragma unroll
    for (int reg = 0; reg < 4; ++reg) {
        int row = wr * 16 + g * 4 + reg;
        float sum = red_s[0][row][0] + red_s[0][row][1];
        float sq  = red_q[0][row][0] + red_q[0][row][1];
        float mean = sum * (1.f / 256.f);
        float var  = sq * (1.f / 256.f) - mean * mean;
        float inv  = rsqrtf(var + 1e-5f);
        #pragma unroll
        for (int hb = 0; hb < 8; ++hb) {
            int col = wc * 128 + hb * 16 + lc;
            out[((size_t)rt * 32 + row) * DD + col] = (vals[hb][reg] - mean) * inv;
        }
    }
}

// ---------------- launch ----------------
extern "C" void kernel_launch(void* const* d_in, const int* in_sizes, int n_in,
                              void* d_out, int out_size, void* d_ws, size_t ws_size,
                              hipStream_t stream) {
    const float* x    = (const float*)d_in[0];
    const int*   mask = (const int*)  d_in[1];
    const float* Wq   = (const float*)d_in[2];
    const float* Wk   = (const float*)d_in[3];
    const float* Wv   = (const float*)d_in[4];
    const float* Wfc  = (const float*)d_in[5];
    const float* W1   = (const float*)d_in[6];
    const float* W2   = (const float*)d_in[7];
    float* out = (float*)d_out;

    const size_t QKV = (size_t)BB * RR * SS * HH;   // 6,291,456 elements
    const size_t BSD = (size_t)BB * SS * DD;        // 4,194,304 elements
    ushort_t* qb  = (ushort_t*)d_ws;                // bf16
    ushort_t* kb  = qb + QKV;
    ushort_t* vb  = kb + QKV;
    ushort_t* ctx = vb + QKV;                       // bf16 [B,6,S,64]
    ushort_t* xb  = ctx + QKV;                      // bf16 [B*S,256]
    ushort_t* wT  = xb + BSD;                       // bf16 [1152,256]
    ushort_t* w1T = wT + (size_t)1152 * 256;        // bf16 [256,256]
    ushort_t* w2T = w1T + 65536;                    // bf16 [256,256]
    ushort_t* wfcT = w2T + 65536;                   // bf16 [6*256,64]

    convert_all_kernel<<<6144, 256, 0, stream>>>(x, Wq, Wk, Wv, Wfc, W1, W2,
                                                 xb, wT, w1T, w2T, wfcT);
    qkv_mfma_kernel  <<<2304, 256, 0, stream>>>(xb, wT, qb, kb, vb);
    attn_mfma_kernel <<<BB * RR * 8, 256, 0, stream>>>(qb, kb, vb, mask, ctx);
    fused_tail_kernel<<<512, 256, 0, stream>>>(ctx, wfcT, x, w1T, w2T, out);
}